// Round 9
// baseline (75.852 us; speedup 1.0000x reference)
//
#include <hip/hip_runtime.h>
#include <math.h>

#define KDIM 32
#define MDIM 256
#define NDIM 2048
#define Z_TOL 1e-6f   // removal threshold (reference semantics)
#define W_TOL 1e-3f   // add threshold (hysteresis: kills z/w deadband cycling,
                      // since w_j = d_j*z_j with d_j <= max diag(AtA) ~ 330 < 1000;
                      // solution shift <= W_TOL/lambda_min ~ 1e-5 << 3e-3)

// ---------------- helpers ----------------
__device__ __forceinline__ float lane_bcast(float x, int lane) {
  // works for both compile-time and wave-uniform SGPR lane index
  return __int_as_float(__builtin_amdgcn_readlane(__float_as_int(x), lane));
}
__device__ __forceinline__ float rcp_newton(float x) {
  float r;
  asm("v_rcp_f32 %0, %1" : "=v"(r) : "v"(x));
  r = r * (2.0f - x * r);  // one Newton step (shared inverse only)
  return r;
}
__device__ __forceinline__ float rcp_fast(float x) {
  float r;
  asm("v_rcp_f32 %0, %1" : "=v"(r) : "v"(x));
  return r;  // ~1 ulp; fine vs 3e-3 threshold (kappa(AtA) ~ 56)
}
// select a[j] for wave-uniform runtime j: 31-cndmask binary tree, depth 5
__device__ __forceinline__ float sel32(const float (&a)[KDIM], int j) {
  float t16[16];
#pragma unroll
  for (int c = 0; c < 16; ++c) t16[c] = ((j >> 4) & 1) ? a[c + 16] : a[c];
  float t8[8];
#pragma unroll
  for (int c = 0; c < 8; ++c) t8[c] = ((j >> 3) & 1) ? t16[c + 8] : t16[c];
  float t4[4];
#pragma unroll
  for (int c = 0; c < 4; ++c) t4[c] = ((j >> 2) & 1) ? t8[c + 4] : t8[c];
  float t2[2];
#pragma unroll
  for (int c = 0; c < 2; ++c) t2[c] = ((j >> 1) & 1) ? t4[c + 2] : t4[c];
  return (j & 1) ? t2[1] : t2[0];
}

// ---------------- AtA partials: 8 blocks, each reduces 32 rows of A ------------
__global__ __launch_bounds__(1024) void ata_partial(const float* __restrict__ A,
                                                    float* __restrict__ part) {
  __shared__ float As[32 * KDIM];  // 4 KB slice
  const int t = threadIdx.x, g = blockIdx.x;
  As[t] = A[g * 32 * KDIM + t];  // coalesced
  __syncthreads();
  const int i = t >> 5, j = t & 31;
  float acc = 0.f;
#pragma unroll
  for (int mm = 0; mm < 32; ++mm)
    acc = fmaf(As[mm * KDIM + i], As[mm * KDIM + j], acc);  // bcast+consecutive: conflict-free
  part[g * 1024 + t] = acc;
}

// ---------------- sum partials -> AtA; full inverse via Gauss-Jordan ----------
__global__ __launch_bounds__(64) void inv_kernel(const float* __restrict__ part,
                                                 float* __restrict__ AtA,
                                                 float* __restrict__ Ainv) {
  __shared__ float AtAs[KDIM * 33];  // padded
  const int l = threadIdx.x;
  const int r = l & 31;
#pragma unroll
  for (int q4 = 0; q4 < 4; ++q4) {
    const int f4 = q4 * 64 + l;
    float4 s = {0.f, 0.f, 0.f, 0.f};
#pragma unroll
    for (int g = 0; g < 8; ++g) {
      const float4 v = reinterpret_cast<const float4*>(part)[g * 256 + f4];
      s.x += v.x; s.y += v.y; s.z += v.z; s.w += v.w;
    }
    reinterpret_cast<float4*>(AtA)[f4] = s;
    const int e = f4 * 4, row = e >> 5, col = e & 31;
    AtAs[row * 33 + col + 0] = s.x;
    AtAs[row * 33 + col + 1] = s.y;
    AtAs[row * 33 + col + 2] = s.z;
    AtAs[row * 33 + col + 3] = s.w;
  }
  __syncthreads();
  float m[KDIM], g[KDIM];
#pragma unroll
  for (int c = 0; c < KDIM; ++c) {
    m[c] = AtAs[r * 33 + c];
    g[c] = (r == c) ? 1.f : 0.f;
  }
  float myinv = 0.f;
#pragma unroll
  for (int j = 0; j < KDIM; ++j) {
    const float inv = rcp_newton(lane_bcast(m[j], j));
    const float f = (r != j) ? m[j] * inv : 0.f;
#pragma unroll
    for (int c = j + 1; c < KDIM; ++c) m[c] = fmaf(-f, lane_bcast(m[c], j), m[c]);
#pragma unroll
    for (int c = 0; c < KDIM; ++c) g[c] = fmaf(-f, lane_bcast(g[c], j), g[c]);
    if (r == j) myinv = inv;
  }
  if (l < 32) {
#pragma unroll
    for (int c = 0; c < KDIM; ++c) Ainv[r * KDIM + c] = myinv * g[c];
  }
}

// ---------------- per-column NNLS, incremental-inverse solver ------------------
// Lane l owns row r=l&31; hi half mirrors lo so all branches are wave-uniform.
// State per column: zero-padded inverse G of the active subsystem (g[32], lane=
// row), iterate z = G*Atb. Active-set flips are exact rank-1 updates (removal:
// Schur downdate; addition: bordering), so sequential flips == re-solve at the
// new P. BPP + hysteresis + Murty control flow identical to the proven R8
// version. One final clean GJ solve (if any flips happened) removes rank-1
// drift so accuracy matches the full-solve version.
__global__ __launch_bounds__(64, 2) void nnls_kernel(const float* __restrict__ A,
                                                     const float* __restrict__ AtA_g,
                                                     const float* __restrict__ Ainv_g,
                                                     const float* __restrict__ X,
                                                     float* __restrict__ S) {
  const int l = threadIdx.x;
  const int r = l & 31;
  const int n = blockIdx.x;

  // ---- Atb = A^T X[:, n] ----
  float x4[4];
#pragma unroll
  for (int q = 0; q < 4; ++q) x4[q] = X[(q * 64 + l) * NDIM + n];
  float cur[KDIM];
#pragma unroll
  for (int k = 0; k < KDIM; ++k) cur[k] = 0.f;
#pragma unroll
  for (int q = 0; q < 4; ++q) {
    const int m = q * 64 + l;
#pragma unroll
    for (int qq = 0; qq < 8; ++qq) {
      const float4 a4 = reinterpret_cast<const float4*>(A + m * KDIM)[qq];
      cur[4 * qq + 0] = fmaf(a4.x, x4[q], cur[4 * qq + 0]);
      cur[4 * qq + 1] = fmaf(a4.y, x4[q], cur[4 * qq + 1]);
      cur[4 * qq + 2] = fmaf(a4.z, x4[q], cur[4 * qq + 2]);
      cur[4 * qq + 3] = fmaf(a4.w, x4[q], cur[4 * qq + 3]);
    }
  }
#pragma unroll
  for (int k = 0; k < KDIM; ++k) cur[k] += __shfl_xor(cur[k], 32);
#pragma unroll
  for (int o = 16; o >= 1; o >>= 1) {
#pragma unroll
    for (int i = 0; i < o; ++i) {
      const bool hi = (l & o) != 0;
      const float a = cur[i], b = cur[i + o];
      const float mine = hi ? b : a;
      const float send = hi ? a : b;
      cur[i] = mine + __shfl_xor(send, o);
    }
  }
  const float atb = cur[0];  // Atb[r], mirrored in hi half

  // ---- shared AtA row; Ainv row -> working inverse g[] ----
  float ata[KDIM], g[KDIM];
#pragma unroll
  for (int q = 0; q < KDIM / 4; ++q) {
    const float4 v = reinterpret_cast<const float4*>(AtA_g + r * KDIM)[q];
    ata[4 * q + 0] = v.x; ata[4 * q + 1] = v.y; ata[4 * q + 2] = v.z; ata[4 * q + 3] = v.w;
    const float4 u = reinterpret_cast<const float4*>(Ainv_g + r * KDIM)[q];
    g[4 * q + 0] = u.x; g[4 * q + 1] = u.y; g[4 * q + 2] = u.z; g[4 * q + 3] = u.w;
  }

  // ---- init: all-active (Atb > 0 in practice): z = Ainv @ Atb ----
  unsigned int P;
  float z = 0.f;
  {
    const unsigned int P0 = (unsigned int)(__ballot(atb > Z_TOL) & 0xffffffffull);
    if (P0 == 0xffffffffu) {
      P = P0;
#pragma unroll
      for (int c = 0; c < KDIM; ++c) z = fmaf(g[c], lane_bcast(atb, c), z);
    } else {
      P = 0u;  // rare path: start empty, additions build G from scratch
#pragma unroll
      for (int c = 0; c < KDIM; ++c) g[c] = 0.f;
    }
  }

  // ---- rank-1 flip primitives (j wave-uniform) ----
  auto removal = [&](int j) {
    const float Grj = sel32(g, j);               // G[r,j] (own row, uniform idx)
    const float Gjj = lane_bcast(Grj, j);
    const float inv = rcp_fast(fmaxf(Gjj, 1e-20f));
    const float zj = lane_bcast(z, j);
    const float fr = Grj * inv;
    z = fmaf(-fr, zj, z);                        // z' = z - G[:,j] z_j / G_jj
#pragma unroll
    for (int c = 0; c < KDIM; ++c)               // G' = G - G[:,j] G[j,:] / G_jj
      g[c] = fmaf(-fr, lane_bcast(g[c], j), g[c]);  // row/col j -> ~0 automatically
  };
  auto addition = [&](int j) {
    const float a = sel32(ata, j);               // a_r = AtA[r,j]
    float u = 0.f;
#pragma unroll
    for (int c = 0; c < KDIM; ++c) u = fmaf(g[c], lane_bcast(a, c), u);  // u = G a
    const float ajj = lane_bcast(a, j);
    float p = u * a;                              // dot over active (u=0 elsewhere)
#pragma unroll
    for (int o = 16; o >= 1; o >>= 1) p += __shfl_xor(p, o);  // half-reduce
    const float sinv = rcp_fast(fmaxf(ajj - p, 1e-20f));      // Schur > 0 (SPD)
    const float t = u - ((r == j) ? 1.f : 0.f);
    float q = t * atb;
#pragma unroll
    for (int o = 16; o >= 1; o >>= 1) q += __shfl_xor(q, o);  // t^T b
    z = fmaf(t, q * sinv, z);                     // z' = z + t (t^T b)/s
    const float ts = t * sinv;
#pragma unroll
    for (int c = 0; c < KDIM; ++c)                // G' = G + t t^T / s
      g[c] = fmaf(t, lane_bcast(ts, c), g[c]);
  };

  // ---- BPP + Murty least-index safeguard + hysteresis (R8-proven control) ----
  int ninf_best = 1000, budget = 3;
  bool dirty = false;
  for (int it = 0; it < 64; ++it) {
    const bool act = (P >> r) & 1u;
    float w = atb;
#pragma unroll
    for (int c = 0; c < KDIM; ++c) w = fmaf(-ata[c], lane_bcast(z, c), w);
    const unsigned int bad = (unsigned int)(__ballot(act && (z <= Z_TOL)) & 0xffffffffull);
    const unsigned int viol = (unsigned int)(__ballot((!act) && (w > W_TOL)) & 0xffffffffull);
    const unsigned int u = bad | viol;
    if (u == 0u) break;  // hysteresis-KKT satisfied (uniform)
    const int ninf = __popc(u);
    bool useblock;
    if (ninf < ninf_best) { ninf_best = ninf; budget = 3; useblock = true; }
    else if (budget > 0) { --budget; useblock = true; }
    else { useblock = false; }
    unsigned int rem, add;
    if (useblock) {
      rem = bad; add = viol;
    } else {
      const unsigned int bm = 1u << (__ffs(u) - 1);  // Murty: least-index flip
      rem = bm & bad; add = bm & ~bad;
    }
    P = (P & ~rem) | add;
    dirty = true;
    while (rem) { const int j = __ffs(rem) - 1; rem &= rem - 1; removal(j); }
    while (add) { const int j = __ffs(add) - 1; add &= add - 1; addition(j); }
  }

  // ---- final clean solve on converged P (removes rank-1 drift) ----
  float zf = z;
  if (dirty) {
    const bool actl = (P >> r) & 1u;
    float m[KDIM];
#pragma unroll
    for (int c = 0; c < KDIM; ++c)
      m[c] = (actl && ((P >> c) & 1u)) ? ata[c] : ((r == c) ? 1.f : 0.f);
    float rhs = actl ? atb : 0.f;
    float myinv = 0.f;
#pragma unroll
    for (int j = 0; j < KDIM; ++j) {
      if ((P >> j) & 1u) {
        const float inv = rcp_fast(lane_bcast(m[j], j));
        const float f = (r != j) ? m[j] * inv : 0.f;
#pragma unroll
        for (int c = j + 1; c < KDIM; ++c) m[c] = fmaf(-f, lane_bcast(m[c], j), m[c]);
        rhs = fmaf(-f, lane_bcast(rhs, j), rhs);
        if (r == j) myinv = inv;
      }
    }
    zf = rhs * myinv;
  }

  if (l < KDIM) S[r * NDIM + n] = ((P >> r) & 1u) ? zf : 0.f;
}

extern "C" void kernel_launch(void* const* d_in, const int* in_sizes, int n_in,
                              void* d_out, int out_size, void* d_ws, size_t ws_size,
                              hipStream_t stream) {
  const float* X = (const float*)d_in[0];  // [256, 2048]
  const float* A = (const float*)d_in[1];  // [256, 32]
  float* S = (float*)d_out;                // [32, 2048]
  float* AtA = (float*)d_ws;               // 1024 floats
  float* Ainv = AtA + KDIM * KDIM;         // 1024 floats
  float* part = Ainv + KDIM * KDIM;        // 8*1024 floats

  ata_partial<<<8, 1024, 0, stream>>>(A, part);
  inv_kernel<<<1, 64, 0, stream>>>(part, AtA, Ainv);
  nnls_kernel<<<NDIM, 64, 0, stream>>>(A, AtA, Ainv, X, S);
}

// Round 10
// 47.821 us; speedup vs baseline: 1.5862x; 1.5862x over previous
//
#include <hip/hip_runtime.h>
#include <math.h>

#define KDIM 32
#define MDIM 256
#define NDIM 2048
#define Z_TOL 1e-6f   // removal threshold (reference semantics)
#define W_TOL 1e-3f   // add threshold (hysteresis: kills z/w deadband cycling,
                      // since w_j = d_j*z_j with d_j <= max diag(AtA) ~ 330 < 1000;
                      // solution shift <= W_TOL/lambda_min ~ 1e-5 << 3e-3)

// ---------------- helpers ----------------
__device__ __forceinline__ float lane_bcast(float x, int lane) {
  return __int_as_float(__builtin_amdgcn_readlane(__float_as_int(x), lane));
}
__device__ __forceinline__ float rcp_newton(float x) {
  float r;
  asm("v_rcp_f32 %0, %1" : "=v"(r) : "v"(x));
  r = r * (2.0f - x * r);  // one Newton step (shared inverse only)
  return r;
}
__device__ __forceinline__ float rcp_fast(float x) {
  float r;
  asm("v_rcp_f32 %0, %1" : "=v"(r) : "v"(x));
  return r;  // ~1 ulp; fine vs 3e-3 threshold (kappa(AtA) ~ 56)
}

// ---------------- AtA partials: 8 blocks, each reduces 32 rows of A ------------
__global__ __launch_bounds__(1024) void ata_partial(const float* __restrict__ A,
                                                    float* __restrict__ part) {
  __shared__ float As[32 * KDIM];  // 4 KB slice
  const int t = threadIdx.x, g = blockIdx.x;
  As[t] = A[g * 32 * KDIM + t];  // coalesced
  __syncthreads();
  const int i = t >> 5, j = t & 31;
  float acc = 0.f;
#pragma unroll
  for (int mm = 0; mm < 32; ++mm)
    acc = fmaf(As[mm * KDIM + i], As[mm * KDIM + j], acc);  // bcast+consecutive: conflict-free
  part[g * 1024 + t] = acc;
}

// ---------------- sum partials -> AtA; full inverse via Gauss-Jordan ----------
__global__ __launch_bounds__(64) void inv_kernel(const float* __restrict__ part,
                                                 float* __restrict__ AtA,
                                                 float* __restrict__ Ainv) {
  __shared__ float AtAs[KDIM * 33];  // padded
  const int l = threadIdx.x;
  const int r = l & 31;
#pragma unroll
  for (int q4 = 0; q4 < 4; ++q4) {
    const int f4 = q4 * 64 + l;
    float4 s = {0.f, 0.f, 0.f, 0.f};
#pragma unroll
    for (int g = 0; g < 8; ++g) {
      const float4 v = reinterpret_cast<const float4*>(part)[g * 256 + f4];
      s.x += v.x; s.y += v.y; s.z += v.z; s.w += v.w;
    }
    reinterpret_cast<float4*>(AtA)[f4] = s;
    const int e = f4 * 4, row = e >> 5, col = e & 31;
    AtAs[row * 33 + col + 0] = s.x;
    AtAs[row * 33 + col + 1] = s.y;
    AtAs[row * 33 + col + 2] = s.z;
    AtAs[row * 33 + col + 3] = s.w;
  }
  __syncthreads();
  float m[KDIM], g[KDIM];
#pragma unroll
  for (int c = 0; c < KDIM; ++c) {
    m[c] = AtAs[r * 33 + c];
    g[c] = (r == c) ? 1.f : 0.f;
  }
  float myinv = 0.f;
#pragma unroll
  for (int j = 0; j < KDIM; ++j) {
    const float inv = rcp_newton(lane_bcast(m[j], j));
    const float f = (r != j) ? m[j] * inv : 0.f;
#pragma unroll
    for (int c = j + 1; c < KDIM; ++c) m[c] = fmaf(-f, lane_bcast(m[c], j), m[c]);
#pragma unroll
    for (int c = 0; c < KDIM; ++c) g[c] = fmaf(-f, lane_bcast(g[c], j), g[c]);
    if (r == j) myinv = inv;
  }
  if (l < 32) {
#pragma unroll
    for (int c = 0; c < KDIM; ++c) Ainv[r * KDIM + c] = myinv * g[c];
  }
}

// ---------------- dual-column NNLS: one wave solves TWO columns ----------------
// Lane l owns row r=l&31 of BOTH columns' systems; hi half mirrors lo, so all
// broadcasts are plain readlane and all branches are wave-uniform (per-column
// predicates come from the lo 32 ballot bits). The two Gauss-Jordan
// eliminations are independent serial chains interleaved in program order ->
// fills the latency bubbles that capped R8 at 38% VALUBusy. Pivot loop runs
// over PA|PB; a pivot absent from one column's set is an exact no-op for it
// (its column is e_j). A converged column re-solves idempotently until its
// partner finishes. Per-column algorithm identical to R8 (BPP + hysteresis +
// Murty least-index safeguard).
__global__ __launch_bounds__(64, 1) void nnls_kernel(const float* __restrict__ A,
                                                     const float* __restrict__ AtA_g,
                                                     const float* __restrict__ Ainv_g,
                                                     const float* __restrict__ X,
                                                     float* __restrict__ S) {
  const int l = threadIdx.x;
  const int r = l & 31;
  const int nA = blockIdx.x * 2, nB = nA + 1;

  // ---- Atb for both columns: shared A loads, float2 X loads (adjacent cols) --
  float2 x2[4];
#pragma unroll
  for (int q = 0; q < 4; ++q)
    x2[q] = *reinterpret_cast<const float2*>(&X[(q * 64 + l) * NDIM + nA]);
  float cA[KDIM], cB[KDIM];
#pragma unroll
  for (int k = 0; k < KDIM; ++k) { cA[k] = 0.f; cB[k] = 0.f; }
#pragma unroll
  for (int q = 0; q < 4; ++q) {
    const int m = q * 64 + l;
#pragma unroll
    for (int qq = 0; qq < 8; ++qq) {
      const float4 a4 = reinterpret_cast<const float4*>(A + m * KDIM)[qq];
      cA[4 * qq + 0] = fmaf(a4.x, x2[q].x, cA[4 * qq + 0]);
      cA[4 * qq + 1] = fmaf(a4.y, x2[q].x, cA[4 * qq + 1]);
      cA[4 * qq + 2] = fmaf(a4.z, x2[q].x, cA[4 * qq + 2]);
      cA[4 * qq + 3] = fmaf(a4.w, x2[q].x, cA[4 * qq + 3]);
      cB[4 * qq + 0] = fmaf(a4.x, x2[q].y, cB[4 * qq + 0]);
      cB[4 * qq + 1] = fmaf(a4.y, x2[q].y, cB[4 * qq + 1]);
      cB[4 * qq + 2] = fmaf(a4.z, x2[q].y, cB[4 * qq + 2]);
      cB[4 * qq + 3] = fmaf(a4.w, x2[q].y, cB[4 * qq + 3]);
    }
  }
  // butterflies: element k -> lane k (hi half mirrored by the off=32 fold)
#pragma unroll
  for (int k = 0; k < KDIM; ++k) {
    cA[k] += __shfl_xor(cA[k], 32);
    cB[k] += __shfl_xor(cB[k], 32);
  }
#pragma unroll
  for (int o = 16; o >= 1; o >>= 1) {
#pragma unroll
    for (int i = 0; i < o; ++i) {
      const bool hi = (l & o) != 0;
      float a = cA[i], b = cA[i + o];
      cA[i] = (hi ? b : a) + __shfl_xor(hi ? a : b, o);
      a = cB[i]; b = cB[i + o];
      cB[i] = (hi ? b : a) + __shfl_xor(hi ? a : b, o);
    }
  }
  const float atbA = cA[0], atbB = cB[0];  // mirrored in hi half

  // ---- shared AtA row + Ainv row ----
  float ata[KDIM], ainv[KDIM];
#pragma unroll
  for (int q = 0; q < KDIM / 4; ++q) {
    const float4 v = reinterpret_cast<const float4*>(AtA_g + r * KDIM)[q];
    ata[4 * q + 0] = v.x; ata[4 * q + 1] = v.y; ata[4 * q + 2] = v.z; ata[4 * q + 3] = v.w;
    const float4 u = reinterpret_cast<const float4*>(Ainv_g + r * KDIM)[q];
    ainv[4 * q + 0] = u.x; ainv[4 * q + 1] = u.y; ainv[4 * q + 2] = u.z; ainv[4 * q + 3] = u.w;
  }

  // ---- init (per column): all-active fast path z = Ainv @ Atb ----
  unsigned int PA, PB;
  float zA = 0.f, zB = 0.f;
  {
    const unsigned int P0A = (unsigned int)(__ballot(atbA > Z_TOL) & 0xffffffffull);
    const unsigned int P0B = (unsigned int)(__ballot(atbB > Z_TOL) & 0xffffffffull);
    if (P0A == 0xffffffffu) {
      PA = P0A;
#pragma unroll
      for (int c = 0; c < KDIM; ++c) zA = fmaf(ainv[c], lane_bcast(atbA, c), zA);
    } else PA = 0u;
    if (P0B == 0xffffffffu) {
      PB = P0B;
#pragma unroll
      for (int c = 0; c < KDIM; ++c) zB = fmaf(ainv[c], lane_bcast(atbB, c), zB);
    } else PB = 0u;
  }

  // dual masked GJ solve: two independent chains, interleaved
  auto solve2 = [&](unsigned int Pa, unsigned int Pb) {
    const bool alA = (Pa >> r) & 1u, alB = (Pb >> r) & 1u;
    float mA[KDIM], mB[KDIM];
#pragma unroll
    for (int c = 0; c < KDIM; ++c) {
      const float av = ata[c];
      const float id = (r == c) ? 1.f : 0.f;
      mA[c] = (alA && ((Pa >> c) & 1u)) ? av : id;
      mB[c] = (alB && ((Pb >> c) & 1u)) ? av : id;
    }
    float rhsA = alA ? atbA : 0.f, rhsB = alB ? atbB : 0.f;
    float miA = 0.f, miB = 0.f;
    const unsigned int PU = Pa | Pb;
#pragma unroll
    for (int j = 0; j < KDIM; ++j) {
      if ((PU >> j) & 1u) {
        const float iA = rcp_fast(lane_bcast(mA[j], j));
        const float iB = rcp_fast(lane_bcast(mB[j], j));
        const float fA = (r != j) ? mA[j] * iA : 0.f;
        const float fB = (r != j) ? mB[j] * iB : 0.f;
#pragma unroll
        for (int c = j + 1; c < KDIM; ++c) {
          mA[c] = fmaf(-fA, lane_bcast(mA[c], j), mA[c]);
          mB[c] = fmaf(-fB, lane_bcast(mB[c], j), mB[c]);
        }
        rhsA = fmaf(-fA, lane_bcast(rhsA, j), rhsA);
        rhsB = fmaf(-fB, lane_bcast(rhsB, j), rhsB);
        if (r == j) { miA = iA; miB = iB; }
      }
    }
    zA = rhsA * miA;  // inactive rows -> 0 (miX stays 0)
    zB = rhsB * miB;
  };

  // ---- BPP + Murty least-index safeguard + hysteresis, both columns lockstep --
  int nbA = 1000, buA = 3, nbB = 1000, buB = 3;
  for (int it = 0; it < 64; ++it) {
    const bool aA = (PA >> r) & 1u, aB = (PB >> r) & 1u;
    const float zmA = aA ? zA : 0.f, zmB = aB ? zB : 0.f;
    float wA = atbA, wB = atbB;
#pragma unroll
    for (int c = 0; c < KDIM; ++c) {
      wA = fmaf(-ata[c], lane_bcast(zmA, c), wA);
      wB = fmaf(-ata[c], lane_bcast(zmB, c), wB);
    }
    const unsigned int badA = (unsigned int)(__ballot(aA && (zA <= Z_TOL)) & 0xffffffffull);
    const unsigned int vioA = (unsigned int)(__ballot((!aA) && (wA > W_TOL)) & 0xffffffffull);
    const unsigned int badB = (unsigned int)(__ballot(aB && (zB <= Z_TOL)) & 0xffffffffull);
    const unsigned int vioB = (unsigned int)(__ballot((!aB) && (wB > W_TOL)) & 0xffffffffull);
    const unsigned int uA = badA | vioA, uB = badB | vioB;
    if ((uA | uB) == 0u) break;  // both KKT-converged (uniform)
    if (uA != 0u) {
      const int ninf = __popc(uA);
      bool blk;
      if (ninf < nbA) { nbA = ninf; buA = 3; blk = true; }
      else if (buA > 0) { --buA; blk = true; }
      else blk = false;
      if (blk) PA = (PA & ~badA) | vioA;
      else { const unsigned int bm = 1u << (__ffs(uA) - 1); PA ^= bm; }
    }
    if (uB != 0u) {
      const int ninf = __popc(uB);
      bool blk;
      if (ninf < nbB) { nbB = ninf; buB = 3; blk = true; }
      else if (buB > 0) { --buB; blk = true; }
      else blk = false;
      if (blk) PB = (PB & ~badB) | vioB;
      else { const unsigned int bm = 1u << (__ffs(uB) - 1); PB ^= bm; }
    }
    solve2(PA, PB);  // converged partner re-solves idempotently (fills bubbles)
  }

  if (l < 32) S[r * NDIM + nA] = ((PA >> r) & 1u) ? zA : 0.f;
  else        S[r * NDIM + nB] = ((PB >> r) & 1u) ? zB : 0.f;
}

extern "C" void kernel_launch(void* const* d_in, const int* in_sizes, int n_in,
                              void* d_out, int out_size, void* d_ws, size_t ws_size,
                              hipStream_t stream) {
  const float* X = (const float*)d_in[0];  // [256, 2048]
  const float* A = (const float*)d_in[1];  // [256, 32]
  float* S = (float*)d_out;                // [32, 2048]
  float* AtA = (float*)d_ws;               // 1024 floats
  float* Ainv = AtA + KDIM * KDIM;         // 1024 floats
  float* part = Ainv + KDIM * KDIM;        // 8*1024 floats

  ata_partial<<<8, 1024, 0, stream>>>(A, part);
  inv_kernel<<<1, 64, 0, stream>>>(part, AtA, Ainv);
  nnls_kernel<<<NDIM / 2, 64, 0, stream>>>(A, AtA, Ainv, X, S);
}

// Round 11
// 43.042 us; speedup vs baseline: 1.7623x; 1.1110x over previous
//
#include <hip/hip_runtime.h>
#include <math.h>

#define KDIM 32
#define MDIM 256
#define NDIM 2048
#define W_TOL 1e-3f   // base add threshold (hysteresis vs z-removal at ~0:
                      // cycling needs sensitivity d_j > W_TOL/Z ~ impossible,
                      // solution shift <= W_TOL/lambda_min ~ 1e-5 << 3e-3)

// ---------------- helpers ----------------
__device__ __forceinline__ float lane_bcast(float x, int lane) {
  return __int_as_float(__builtin_amdgcn_readlane(__float_as_int(x), lane));
}
__device__ __forceinline__ float rcp_newton(float x) {
  float r;
  asm("v_rcp_f32 %0, %1" : "=v"(r) : "v"(x));
  r = r * (2.0f - x * r);  // one Newton step (shared inverse only)
  return r;
}
__device__ __forceinline__ float rcp_fast(float x) {
  float r;
  asm("v_rcp_f32 %0, %1" : "=v"(r) : "v"(x));
  return r;  // ~1 ulp; fine vs 3e-3 threshold (kappa(AtA) ~ 56)
}

// ---------------- AtA partials: 8 blocks, each reduces 32 rows of A ------------
__global__ __launch_bounds__(1024) void ata_partial(const float* __restrict__ A,
                                                    float* __restrict__ part) {
  __shared__ float As[32 * KDIM];  // 4 KB slice
  const int t = threadIdx.x, g = blockIdx.x;
  As[t] = A[g * 32 * KDIM + t];  // coalesced
  __syncthreads();
  const int i = t >> 5, j = t & 31;
  float acc = 0.f;
#pragma unroll
  for (int mm = 0; mm < 32; ++mm)
    acc = fmaf(As[mm * KDIM + i], As[mm * KDIM + j], acc);  // bcast+consecutive: conflict-free
  part[g * 1024 + t] = acc;
}

// ---------------- sum partials -> AtA; full inverse via Gauss-Jordan ----------
__global__ __launch_bounds__(64) void inv_kernel(const float* __restrict__ part,
                                                 float* __restrict__ AtA,
                                                 float* __restrict__ Ainv) {
  __shared__ float AtAs[KDIM * 33];  // padded
  const int l = threadIdx.x;
  const int r = l & 31;
#pragma unroll
  for (int q4 = 0; q4 < 4; ++q4) {
    const int f4 = q4 * 64 + l;
    float4 s = {0.f, 0.f, 0.f, 0.f};
#pragma unroll
    for (int g = 0; g < 8; ++g) {
      const float4 v = reinterpret_cast<const float4*>(part)[g * 256 + f4];
      s.x += v.x; s.y += v.y; s.z += v.z; s.w += v.w;
    }
    reinterpret_cast<float4*>(AtA)[f4] = s;
    const int e = f4 * 4, row = e >> 5, col = e & 31;
    AtAs[row * 33 + col + 0] = s.x;
    AtAs[row * 33 + col + 1] = s.y;
    AtAs[row * 33 + col + 2] = s.z;
    AtAs[row * 33 + col + 3] = s.w;
  }
  __syncthreads();
  float m[KDIM], g[KDIM];
#pragma unroll
  for (int c = 0; c < KDIM; ++c) {
    m[c] = AtAs[r * 33 + c];
    g[c] = (r == c) ? 1.f : 0.f;
  }
  float myinv = 0.f;
#pragma unroll
  for (int j = 0; j < KDIM; ++j) {
    const float inv = rcp_newton(lane_bcast(m[j], j));
    const float f = (r != j) ? m[j] * inv : 0.f;
#pragma unroll
    for (int c = j + 1; c < KDIM; ++c) m[c] = fmaf(-f, lane_bcast(m[c], j), m[c]);
#pragma unroll
    for (int c = 0; c < KDIM; ++c) g[c] = fmaf(-f, lane_bcast(g[c], j), g[c]);
    if (r == j) myinv = inv;
  }
  if (l < 32) {
#pragma unroll
    for (int c = 0; c < KDIM; ++c) Ainv[r * KDIM + c] = myinv * g[c];
  }
}

// ---------------- per-column NNLS, one wave per column -------------------------
// Lane l owns row r=l&31; hi half mirrors lo so all branches are wave-uniform.
// Solver: annealed-threshold block principal pivoting (no single-flip fallback).
// bad = {active: z < -zeps}, viol = {inactive: w > weps}; on 2 stagnant rounds
// (ninf not strictly improving) escalate zeps (capped 2.5e-4) and weps (x4).
// Escalation strictly shrinks the infeasible set; once weps > max residual the
// rounds are pure removals -> P shrinks monotonically -> guaranteed finite,
// no Murty tail. Output clips retained small negatives: err <= zeps + shifts
// << 3e-3. Masked solves: all-register Gauss-Jordan with readlane broadcasts.
__global__ __launch_bounds__(64, 2) void nnls_kernel(const float* __restrict__ A,
                                                     const float* __restrict__ AtA_g,
                                                     const float* __restrict__ Ainv_g,
                                                     const float* __restrict__ X,
                                                     float* __restrict__ S) {
  const int l = threadIdx.x;
  const int r = l & 31;
  const int n = blockIdx.x;

  // ---- Atb = A^T X[:, n] ----
  float x4[4];
#pragma unroll
  for (int q = 0; q < 4; ++q) x4[q] = X[(q * 64 + l) * NDIM + n];
  float cur[KDIM];
#pragma unroll
  for (int k = 0; k < KDIM; ++k) cur[k] = 0.f;
#pragma unroll
  for (int q = 0; q < 4; ++q) {
    const int m = q * 64 + l;
#pragma unroll
    for (int qq = 0; qq < 8; ++qq) {
      const float4 a4 = reinterpret_cast<const float4*>(A + m * KDIM)[qq];
      cur[4 * qq + 0] = fmaf(a4.x, x4[q], cur[4 * qq + 0]);
      cur[4 * qq + 1] = fmaf(a4.y, x4[q], cur[4 * qq + 1]);
      cur[4 * qq + 2] = fmaf(a4.z, x4[q], cur[4 * qq + 2]);
      cur[4 * qq + 3] = fmaf(a4.w, x4[q], cur[4 * qq + 3]);
    }
  }
#pragma unroll
  for (int k = 0; k < KDIM; ++k) cur[k] += __shfl_xor(cur[k], 32);
#pragma unroll
  for (int o = 16; o >= 1; o >>= 1) {
#pragma unroll
    for (int i = 0; i < o; ++i) {
      const bool hi = (l & o) != 0;
      const float a = cur[i], b = cur[i + o];
      const float mine = hi ? b : a;
      const float send = hi ? a : b;
      cur[i] = mine + __shfl_xor(send, o);
    }
  }
  const float atb = cur[0];  // Atb[r], mirrored in hi half

  // ---- shared AtA row + Ainv row ----
  float ata[KDIM], ainv[KDIM];
#pragma unroll
  for (int q = 0; q < KDIM / 4; ++q) {
    const float4 v = reinterpret_cast<const float4*>(AtA_g + r * KDIM)[q];
    ata[4 * q + 0] = v.x; ata[4 * q + 1] = v.y; ata[4 * q + 2] = v.z; ata[4 * q + 3] = v.w;
    const float4 u = reinterpret_cast<const float4*>(Ainv_g + r * KDIM)[q];
    ainv[4 * q + 0] = u.x; ainv[4 * q + 1] = u.y; ainv[4 * q + 2] = u.z; ainv[4 * q + 3] = u.w;
  }

  // masked solve via Gauss-Jordan (registers + readlane; inactive pivots skipped)
  auto solve = [&](unsigned int Pm) -> float {
    const bool actl = (Pm >> r) & 1u;
    float m[KDIM];
#pragma unroll
    for (int c = 0; c < KDIM; ++c)
      m[c] = (actl && ((Pm >> c) & 1u)) ? ata[c] : ((r == c) ? 1.f : 0.f);
    float rhs = actl ? atb : 0.f;
    float myinv = 0.f;
#pragma unroll
    for (int j = 0; j < KDIM; ++j) {
      if ((Pm >> j) & 1u) {
        const float inv = rcp_fast(lane_bcast(m[j], j));
        const float f = (r != j) ? m[j] * inv : 0.f;
#pragma unroll
        for (int c = j + 1; c < KDIM; ++c) m[c] = fmaf(-f, lane_bcast(m[c], j), m[c]);
        rhs = fmaf(-f, lane_bcast(rhs, j), rhs);
        if (r == j) myinv = inv;
      }
    }
    return rhs * myinv;  // inactive rows -> 0
  };

  // ---- init: all-active fast path z = Ainv @ Atb (4 chains for latency) ----
  unsigned int P;
  float z = 0.f;
  {
    const unsigned int P0 = (unsigned int)(__ballot(atb > 1e-6f) & 0xffffffffull);
    if (P0 == 0xffffffffu) {
      P = P0;
      float s0 = 0.f, s1 = 0.f, s2 = 0.f, s3 = 0.f;
#pragma unroll
      for (int c = 0; c < KDIM; c += 4) {
        s0 = fmaf(ainv[c + 0], lane_bcast(atb, c + 0), s0);
        s1 = fmaf(ainv[c + 1], lane_bcast(atb, c + 1), s1);
        s2 = fmaf(ainv[c + 2], lane_bcast(atb, c + 2), s2);
        s3 = fmaf(ainv[c + 3], lane_bcast(atb, c + 3), s3);
      }
      z = (s0 + s1) + (s2 + s3);
    } else {
      P = 0u;
      z = 0.f;
    }
  }

  // ---- annealed-threshold block principal pivoting ----
  float zeps = 0.f, weps = W_TOL;
  int best = 1000, stag = 0;
  for (int it = 0; it < 64; ++it) {
    const bool act = (P >> r) & 1u;
    // w = atb - AtA z  (z is 0 on inactive rows), 4 chains for latency
    float s0 = 0.f, s1 = 0.f, s2 = 0.f, s3 = 0.f;
#pragma unroll
    for (int c = 0; c < KDIM; c += 4) {
      s0 = fmaf(ata[c + 0], lane_bcast(z, c + 0), s0);
      s1 = fmaf(ata[c + 1], lane_bcast(z, c + 1), s1);
      s2 = fmaf(ata[c + 2], lane_bcast(z, c + 2), s2);
      s3 = fmaf(ata[c + 3], lane_bcast(z, c + 3), s3);
    }
    const float w = atb - ((s0 + s1) + (s2 + s3));
    const unsigned int bad = (unsigned int)(__ballot(act && (z < -zeps)) & 0xffffffffull);
    const unsigned int viol = (unsigned int)(__ballot((!act) && (w > weps)) & 0xffffffffull);
    const unsigned int u = bad | viol;
    if (u == 0u) break;  // annealed-KKT satisfied (uniform)
    const int ninf = __popc(u);
    if (ninf < best) {
      best = ninf;
      stag = 0;
    } else if (++stag >= 2) {  // stagnation: escalate thresholds, keep blocking
      zeps = fminf(zeps * 4.f + 2e-6f, 2.5e-4f);
      weps *= 4.f;
      stag = 0;
    }
    P = (P & ~bad) | viol;
    z = solve(P);
  }

  if (l < KDIM) S[r * NDIM + n] = ((P >> r) & 1u) ? fmaxf(z, 0.f) : 0.f;
}

extern "C" void kernel_launch(void* const* d_in, const int* in_sizes, int n_in,
                              void* d_out, int out_size, void* d_ws, size_t ws_size,
                              hipStream_t stream) {
  const float* X = (const float*)d_in[0];  // [256, 2048]
  const float* A = (const float*)d_in[1];  // [256, 32]
  float* S = (float*)d_out;                // [32, 2048]
  float* AtA = (float*)d_ws;               // 1024 floats
  float* Ainv = AtA + KDIM * KDIM;         // 1024 floats
  float* part = Ainv + KDIM * KDIM;        // 8*1024 floats

  ata_partial<<<8, 1024, 0, stream>>>(A, part);
  inv_kernel<<<1, 64, 0, stream>>>(part, AtA, Ainv);
  nnls_kernel<<<NDIM, 64, 0, stream>>>(A, AtA, Ainv, X, S);
}

// Round 12
// 41.430 us; speedup vs baseline: 1.8309x; 1.0389x over previous
//
#include <hip/hip_runtime.h>
#include <math.h>

#define KDIM 32
#define MDIM 256
#define NDIM 2048
#define W_TOL 1e-3f   // base add threshold (hysteresis vs z-removal at ~0:
                      // cycling needs sensitivity d_j > W_TOL/Z ~ impossible,
                      // solution shift <= W_TOL/lambda_min ~ 1e-5 << 3e-3)

// ---------------- helpers ----------------
__device__ __forceinline__ float lane_bcast(float x, int lane) {
  return __int_as_float(__builtin_amdgcn_readlane(__float_as_int(x), lane));
}
__device__ __forceinline__ float rcp_newton(float x) {
  float r;
  asm("v_rcp_f32 %0, %1" : "=v"(r) : "v"(x));
  r = r * (2.0f - x * r);  // one Newton step (shared inverse only)
  return r;
}
__device__ __forceinline__ float rcp_fast(float x) {
  float r;
  asm("v_rcp_f32 %0, %1" : "=v"(r) : "v"(x));
  return r;  // ~1 ulp; fine vs 3e-3 threshold (kappa ~ 56 both modes)
}

// ---------------- AtA partials: 8 blocks, each reduces 32 rows of A ------------
__global__ __launch_bounds__(1024) void ata_partial(const float* __restrict__ A,
                                                    float* __restrict__ part) {
  __shared__ float As[32 * KDIM];  // 4 KB slice
  const int t = threadIdx.x, g = blockIdx.x;
  As[t] = A[g * 32 * KDIM + t];  // coalesced
  __syncthreads();
  const int i = t >> 5, j = t & 31;
  float acc = 0.f;
#pragma unroll
  for (int mm = 0; mm < 32; ++mm)
    acc = fmaf(As[mm * KDIM + i], As[mm * KDIM + j], acc);  // bcast+consecutive: conflict-free
  part[g * 1024 + t] = acc;
}

// ---------------- sum partials -> AtA; full inverse via Gauss-Jordan ----------
__global__ __launch_bounds__(64) void inv_kernel(const float* __restrict__ part,
                                                 float* __restrict__ AtA,
                                                 float* __restrict__ Ainv) {
  __shared__ float AtAs[KDIM * 33];  // padded
  const int l = threadIdx.x;
  const int r = l & 31;
#pragma unroll
  for (int q4 = 0; q4 < 4; ++q4) {
    const int f4 = q4 * 64 + l;
    float4 s = {0.f, 0.f, 0.f, 0.f};
#pragma unroll
    for (int g = 0; g < 8; ++g) {
      const float4 v = reinterpret_cast<const float4*>(part)[g * 256 + f4];
      s.x += v.x; s.y += v.y; s.z += v.z; s.w += v.w;
    }
    reinterpret_cast<float4*>(AtA)[f4] = s;
    const int e = f4 * 4, row = e >> 5, col = e & 31;
    AtAs[row * 33 + col + 0] = s.x;
    AtAs[row * 33 + col + 1] = s.y;
    AtAs[row * 33 + col + 2] = s.z;
    AtAs[row * 33 + col + 3] = s.w;
  }
  __syncthreads();
  float m[KDIM], g[KDIM];
#pragma unroll
  for (int c = 0; c < KDIM; ++c) {
    m[c] = AtAs[r * 33 + c];
    g[c] = (r == c) ? 1.f : 0.f;
  }
  float myinv = 0.f;
#pragma unroll
  for (int j = 0; j < KDIM; ++j) {
    const float inv = rcp_newton(lane_bcast(m[j], j));
    const float f = (r != j) ? m[j] * inv : 0.f;
#pragma unroll
    for (int c = j + 1; c < KDIM; ++c) m[c] = fmaf(-f, lane_bcast(m[c], j), m[c]);
#pragma unroll
    for (int c = 0; c < KDIM; ++c) g[c] = fmaf(-f, lane_bcast(g[c], j), g[c]);
    if (r == j) myinv = inv;
  }
  if (l < 32) {
#pragma unroll
    for (int c = 0; c < KDIM; ++c) Ainv[r * KDIM + c] = myinv * g[c];
  }
}

// ---------------- per-column NNLS, one wave per column -------------------------
// Lane l owns row r=l&31; hi half mirrors lo so all branches are wave-uniform.
// Solver: annealed-threshold block principal pivoting (R11-proven control flow).
// Masked solves pick the cheaper of two exact formulations:
//   p <= q: Gauss-Jordan on the p x p active subsystem of AtA (rhs = Atb).
//   p >  q: dual path via the shared full inverse G = AtA^-1 and y = G Atb:
//           solve G_RR u_R = y_R (q x q GJ on G), then z = y - G[:,R] u.
//           Exact identity => same fixed point; z on removed rows ~1e-7,
//           w-error <= ||AtA||*1e-7 ~ 3e-5 << weps. G_RR SPD, kappa <= 56.
__global__ __launch_bounds__(64, 2) void nnls_kernel(const float* __restrict__ A,
                                                     const float* __restrict__ AtA_g,
                                                     const float* __restrict__ Ainv_g,
                                                     const float* __restrict__ X,
                                                     float* __restrict__ S) {
  const int l = threadIdx.x;
  const int r = l & 31;
  const int n = blockIdx.x;

  // ---- Atb = A^T X[:, n] ----
  float x4[4];
#pragma unroll
  for (int q = 0; q < 4; ++q) x4[q] = X[(q * 64 + l) * NDIM + n];
  float cur[KDIM];
#pragma unroll
  for (int k = 0; k < KDIM; ++k) cur[k] = 0.f;
#pragma unroll
  for (int q = 0; q < 4; ++q) {
    const int m = q * 64 + l;
#pragma unroll
    for (int qq = 0; qq < 8; ++qq) {
      const float4 a4 = reinterpret_cast<const float4*>(A + m * KDIM)[qq];
      cur[4 * qq + 0] = fmaf(a4.x, x4[q], cur[4 * qq + 0]);
      cur[4 * qq + 1] = fmaf(a4.y, x4[q], cur[4 * qq + 1]);
      cur[4 * qq + 2] = fmaf(a4.z, x4[q], cur[4 * qq + 2]);
      cur[4 * qq + 3] = fmaf(a4.w, x4[q], cur[4 * qq + 3]);
    }
  }
#pragma unroll
  for (int k = 0; k < KDIM; ++k) cur[k] += __shfl_xor(cur[k], 32);
#pragma unroll
  for (int o = 16; o >= 1; o >>= 1) {
#pragma unroll
    for (int i = 0; i < o; ++i) {
      const bool hi = (l & o) != 0;
      const float a = cur[i], b = cur[i + o];
      const float mine = hi ? b : a;
      const float send = hi ? a : b;
      cur[i] = mine + __shfl_xor(send, o);
    }
  }
  const float atb = cur[0];  // Atb[r], mirrored in hi half

  // ---- shared AtA row + Ainv row ----
  float ata[KDIM], g[KDIM];
#pragma unroll
  for (int q = 0; q < KDIM / 4; ++q) {
    const float4 v = reinterpret_cast<const float4*>(AtA_g + r * KDIM)[q];
    ata[4 * q + 0] = v.x; ata[4 * q + 1] = v.y; ata[4 * q + 2] = v.z; ata[4 * q + 3] = v.w;
    const float4 u = reinterpret_cast<const float4*>(Ainv_g + r * KDIM)[q];
    g[4 * q + 0] = u.x; g[4 * q + 1] = u.y; g[4 * q + 2] = u.z; g[4 * q + 3] = u.w;
  }

  // ---- y = Ainv @ Atb (unconstrained solution; 4 chains for latency) ----
  float y;
  {
    float s0 = 0.f, s1 = 0.f, s2 = 0.f, s3 = 0.f;
#pragma unroll
    for (int c = 0; c < KDIM; c += 4) {
      s0 = fmaf(g[c + 0], lane_bcast(atb, c + 0), s0);
      s1 = fmaf(g[c + 1], lane_bcast(atb, c + 1), s1);
      s2 = fmaf(g[c + 2], lane_bcast(atb, c + 2), s2);
      s3 = fmaf(g[c + 3], lane_bcast(atb, c + 3), s3);
    }
    y = (s0 + s1) + (s2 + s3);
  }

  // masked solve, min(p,q)-pivot dual formulation (registers + readlane only)
  auto solve_dual = [&](unsigned int Pm) -> float {
    const unsigned int Rm = ~Pm;  // removed set (bits 0..31)
    const int p = __popc(Pm);
    if (p <= 32 - p) {
      // ---- active-set GJ on AtA ----
      const bool actl = (Pm >> r) & 1u;
      float m[KDIM];
#pragma unroll
      for (int c = 0; c < KDIM; ++c)
        m[c] = (actl && ((Pm >> c) & 1u)) ? ata[c] : ((r == c) ? 1.f : 0.f);
      float rhs = actl ? atb : 0.f;
      float myinv = 0.f;
#pragma unroll
      for (int j = 0; j < KDIM; ++j) {
        if ((Pm >> j) & 1u) {
          const float inv = rcp_fast(lane_bcast(m[j], j));
          const float f = (r != j) ? m[j] * inv : 0.f;
#pragma unroll
          for (int c = j + 1; c < KDIM; ++c) m[c] = fmaf(-f, lane_bcast(m[c], j), m[c]);
          rhs = fmaf(-f, lane_bcast(rhs, j), rhs);
          if (r == j) myinv = inv;
        }
      }
      return rhs * myinv;  // inactive rows -> exact 0
    } else {
      // ---- removed-set GJ on G = AtA^-1: G_RR u = y_R; z = y - G[:,R] u ----
      const bool reml = (Rm >> r) & 1u;
      float m[KDIM];
#pragma unroll
      for (int c = 0; c < KDIM; ++c)
        m[c] = (reml && ((Rm >> c) & 1u)) ? g[c] : ((r == c) ? 1.f : 0.f);
      float rhs = reml ? y : 0.f;
      float myinv = 0.f;
#pragma unroll
      for (int j = 0; j < KDIM; ++j) {
        if ((Rm >> j) & 1u) {
          const float inv = rcp_fast(lane_bcast(m[j], j));
          const float f = (r != j) ? m[j] * inv : 0.f;
#pragma unroll
          for (int c = j + 1; c < KDIM; ++c) m[c] = fmaf(-f, lane_bcast(m[c], j), m[c]);
          rhs = fmaf(-f, lane_bcast(rhs, j), rhs);
          if (r == j) myinv = inv;
        }
      }
      const float u = rhs * myinv;  // u_c = 0 for c notin R
      float z0 = y, z1 = 0.f, z2 = 0.f, z3 = 0.f;
#pragma unroll
      for (int c = 0; c < KDIM; c += 4) {
        z0 = fmaf(-g[c + 0], lane_bcast(u, c + 0), z0);
        z1 = fmaf(-g[c + 1], lane_bcast(u, c + 1), z1);
        z2 = fmaf(-g[c + 2], lane_bcast(u, c + 2), z2);
        z3 = fmaf(-g[c + 3], lane_bcast(u, c + 3), z3);
      }
      return (z0 + z1) + (z2 + z3);  // removed rows -> ~0 (roundoff only)
    }
  };

  // ---- init ----
  unsigned int P = (unsigned int)(__ballot(atb > 1e-6f) & 0xffffffffull);
  float z = (P == 0xffffffffu) ? y : solve_dual(P);

  // ---- annealed-threshold block principal pivoting ----
  float zeps = 0.f, weps = W_TOL;
  int best = 1000, stag = 0;
  for (int it = 0; it < 64; ++it) {
    const bool act = (P >> r) & 1u;
    // w = atb - AtA z (z ~0 on inactive rows), 4 chains for latency
    float s0 = 0.f, s1 = 0.f, s2 = 0.f, s3 = 0.f;
#pragma unroll
    for (int c = 0; c < KDIM; c += 4) {
      s0 = fmaf(ata[c + 0], lane_bcast(z, c + 0), s0);
      s1 = fmaf(ata[c + 1], lane_bcast(z, c + 1), s1);
      s2 = fmaf(ata[c + 2], lane_bcast(z, c + 2), s2);
      s3 = fmaf(ata[c + 3], lane_bcast(z, c + 3), s3);
    }
    const float w = atb - ((s0 + s1) + (s2 + s3));
    const unsigned int bad = (unsigned int)(__ballot(act && (z < -zeps)) & 0xffffffffull);
    const unsigned int viol = (unsigned int)(__ballot((!act) && (w > weps)) & 0xffffffffull);
    const unsigned int u = bad | viol;
    if (u == 0u) break;  // annealed-KKT satisfied (uniform)
    const int ninf = __popc(u);
    if (ninf < best) {
      best = ninf;
      stag = 0;
    } else if (++stag >= 2) {  // stagnation: escalate thresholds, keep blocking
      zeps = fminf(zeps * 4.f + 2e-6f, 2.5e-4f);
      weps *= 4.f;
      stag = 0;
    }
    P = (P & ~bad) | viol;
    z = solve_dual(P);
  }

  if (l < KDIM) S[r * NDIM + n] = ((P >> r) & 1u) ? fmaxf(z, 0.f) : 0.f;
}

extern "C" void kernel_launch(void* const* d_in, const int* in_sizes, int n_in,
                              void* d_out, int out_size, void* d_ws, size_t ws_size,
                              hipStream_t stream) {
  const float* X = (const float*)d_in[0];  // [256, 2048]
  const float* A = (const float*)d_in[1];  // [256, 32]
  float* S = (float*)d_out;                // [32, 2048]
  float* AtA = (float*)d_ws;               // 1024 floats
  float* Ainv = AtA + KDIM * KDIM;         // 1024 floats
  float* part = Ainv + KDIM * KDIM;        // 8*1024 floats

  ata_partial<<<8, 1024, 0, stream>>>(A, part);
  inv_kernel<<<1, 64, 0, stream>>>(part, AtA, Ainv);
  nnls_kernel<<<NDIM, 64, 0, stream>>>(A, AtA, Ainv, X, S);
}

// Round 13
// 41.154 us; speedup vs baseline: 1.8431x; 1.0067x over previous
//
#include <hip/hip_runtime.h>
#include <math.h>

#define KDIM 32
#define MDIM 256
#define NDIM 2048
#define W_TOL 1e-3f   // base add threshold (hysteresis vs z-removal at ~0:
                      // cycling needs sensitivity d_j > W_TOL/Z ~ impossible,
                      // solution shift <= W_TOL/lambda_min ~ 1e-5 << 3e-3)

// ---------------- helpers ----------------
__device__ __forceinline__ float lane_bcast(float x, int lane) {
  return __int_as_float(__builtin_amdgcn_readlane(__float_as_int(x), lane));
}
__device__ __forceinline__ float rcp_newton(float x) {
  float r;
  asm("v_rcp_f32 %0, %1" : "=v"(r) : "v"(x));
  r = r * (2.0f - x * r);  // one Newton step (shared inverse only)
  return r;
}
__device__ __forceinline__ float rcp_fast(float x) {
  float r;
  asm("v_rcp_f32 %0, %1" : "=v"(r) : "v"(x));
  return r;  // ~1 ulp; fine vs 3e-3 threshold (kappa ~ 56 both modes)
}

// ---------------- AtA partials: 8 blocks, each reduces 32 rows of A ------------
__global__ __launch_bounds__(1024) void ata_partial(const float* __restrict__ A,
                                                    float* __restrict__ part) {
  __shared__ float As[32 * KDIM];  // 4 KB slice
  const int t = threadIdx.x, g = blockIdx.x;
  As[t] = A[g * 32 * KDIM + t];  // coalesced
  __syncthreads();
  const int i = t >> 5, j = t & 31;
  float acc = 0.f;
#pragma unroll
  for (int mm = 0; mm < 32; ++mm)
    acc = fmaf(As[mm * KDIM + i], As[mm * KDIM + j], acc);  // bcast+consecutive: conflict-free
  part[g * 1024 + t] = acc;
}

// ---------------- sum partials -> AtA; full inverse via Gauss-Jordan ----------
__global__ __launch_bounds__(64) void inv_kernel(const float* __restrict__ part,
                                                 float* __restrict__ AtA,
                                                 float* __restrict__ Ainv) {
  __shared__ float AtAs[KDIM * 33];  // padded
  const int l = threadIdx.x;
  const int r = l & 31;
#pragma unroll
  for (int q4 = 0; q4 < 4; ++q4) {
    const int f4 = q4 * 64 + l;
    float4 s = {0.f, 0.f, 0.f, 0.f};
#pragma unroll
    for (int g = 0; g < 8; ++g) {
      const float4 v = reinterpret_cast<const float4*>(part)[g * 256 + f4];
      s.x += v.x; s.y += v.y; s.z += v.z; s.w += v.w;
    }
    reinterpret_cast<float4*>(AtA)[f4] = s;
    const int e = f4 * 4, row = e >> 5, col = e & 31;
    AtAs[row * 33 + col + 0] = s.x;
    AtAs[row * 33 + col + 1] = s.y;
    AtAs[row * 33 + col + 2] = s.z;
    AtAs[row * 33 + col + 3] = s.w;
  }
  __syncthreads();
  float m[KDIM], g[KDIM];
#pragma unroll
  for (int c = 0; c < KDIM; ++c) {
    m[c] = AtAs[r * 33 + c];
    g[c] = (r == c) ? 1.f : 0.f;
  }
  float myinv = 0.f;
#pragma unroll
  for (int j = 0; j < KDIM; ++j) {
    const float inv = rcp_newton(lane_bcast(m[j], j));
    const float f = (r != j) ? m[j] * inv : 0.f;
#pragma unroll
    for (int c = j + 1; c < KDIM; ++c) m[c] = fmaf(-f, lane_bcast(m[c], j), m[c]);
#pragma unroll
    for (int c = 0; c < KDIM; ++c) g[c] = fmaf(-f, lane_bcast(g[c], j), g[c]);
    if (r == j) myinv = inv;
  }
  if (l < 32) {
#pragma unroll
    for (int c = 0; c < KDIM; ++c) Ainv[r * KDIM + c] = myinv * g[c];
  }
}

// ---------------- per-column NNLS, one wave per column -------------------------
// Lane l owns row r=l&31; hi half mirrors lo so all branches are wave-uniform.
// Solver: annealed-threshold block principal pivoting. Thresholds escalate on
// EVERY non-improving round (stag>=1); each escalation strictly shrinks the
// infeasible set; once weps > max residual only removals remain -> terminates
// well inside the 24-iteration cap (straggler waves previously saturated the
// cap, so cap*chain IS the kernel duration). Masked solves pick the cheaper of
// two exact formulations (min(p,q) pivots): active-set GJ on AtA, or dual
// removed-set GJ on G = AtA^-1 (z = y - G[:,R] (G_RR)^-1 y_R).
__global__ __launch_bounds__(64, 2) void nnls_kernel(const float* __restrict__ A,
                                                     const float* __restrict__ AtA_g,
                                                     const float* __restrict__ Ainv_g,
                                                     const float* __restrict__ X,
                                                     float* __restrict__ S) {
  const int l = threadIdx.x;
  const int r = l & 31;
  const int n = blockIdx.x;

  // ---- Atb = A^T X[:, n] ----
  float x4[4];
#pragma unroll
  for (int q = 0; q < 4; ++q) x4[q] = X[(q * 64 + l) * NDIM + n];
  float cur[KDIM];
#pragma unroll
  for (int k = 0; k < KDIM; ++k) cur[k] = 0.f;
#pragma unroll
  for (int q = 0; q < 4; ++q) {
    const int m = q * 64 + l;
#pragma unroll
    for (int qq = 0; qq < 8; ++qq) {
      const float4 a4 = reinterpret_cast<const float4*>(A + m * KDIM)[qq];
      cur[4 * qq + 0] = fmaf(a4.x, x4[q], cur[4 * qq + 0]);
      cur[4 * qq + 1] = fmaf(a4.y, x4[q], cur[4 * qq + 1]);
      cur[4 * qq + 2] = fmaf(a4.z, x4[q], cur[4 * qq + 2]);
      cur[4 * qq + 3] = fmaf(a4.w, x4[q], cur[4 * qq + 3]);
    }
  }
#pragma unroll
  for (int k = 0; k < KDIM; ++k) cur[k] += __shfl_xor(cur[k], 32);
#pragma unroll
  for (int o = 16; o >= 1; o >>= 1) {
#pragma unroll
    for (int i = 0; i < o; ++i) {
      const bool hi = (l & o) != 0;
      const float a = cur[i], b = cur[i + o];
      const float mine = hi ? b : a;
      const float send = hi ? a : b;
      cur[i] = mine + __shfl_xor(send, o);
    }
  }
  const float atb = cur[0];  // Atb[r], mirrored in hi half

  // ---- shared AtA row + Ainv row ----
  float ata[KDIM], g[KDIM];
#pragma unroll
  for (int q = 0; q < KDIM / 4; ++q) {
    const float4 v = reinterpret_cast<const float4*>(AtA_g + r * KDIM)[q];
    ata[4 * q + 0] = v.x; ata[4 * q + 1] = v.y; ata[4 * q + 2] = v.z; ata[4 * q + 3] = v.w;
    const float4 u = reinterpret_cast<const float4*>(Ainv_g + r * KDIM)[q];
    g[4 * q + 0] = u.x; g[4 * q + 1] = u.y; g[4 * q + 2] = u.z; g[4 * q + 3] = u.w;
  }

  // ---- y = Ainv @ Atb (unconstrained solution; 4 chains for latency) ----
  float y;
  {
    float s0 = 0.f, s1 = 0.f, s2 = 0.f, s3 = 0.f;
#pragma unroll
    for (int c = 0; c < KDIM; c += 4) {
      s0 = fmaf(g[c + 0], lane_bcast(atb, c + 0), s0);
      s1 = fmaf(g[c + 1], lane_bcast(atb, c + 1), s1);
      s2 = fmaf(g[c + 2], lane_bcast(atb, c + 2), s2);
      s3 = fmaf(g[c + 3], lane_bcast(atb, c + 3), s3);
    }
    y = (s0 + s1) + (s2 + s3);
  }

  // masked solve, min(p,q)-pivot dual formulation (registers + readlane only)
  auto solve_dual = [&](unsigned int Pm) -> float {
    const unsigned int Rm = ~Pm;  // removed set (bits 0..31)
    const int p = __popc(Pm);
    if (p <= 32 - p) {
      // ---- active-set GJ on AtA ----
      const bool actl = (Pm >> r) & 1u;
      float m[KDIM];
#pragma unroll
      for (int c = 0; c < KDIM; ++c)
        m[c] = (actl && ((Pm >> c) & 1u)) ? ata[c] : ((r == c) ? 1.f : 0.f);
      float rhs = actl ? atb : 0.f;
      float myinv = 0.f;
#pragma unroll
      for (int j = 0; j < KDIM; ++j) {
        if ((Pm >> j) & 1u) {
          const float inv = rcp_fast(lane_bcast(m[j], j));
          const float f = (r != j) ? m[j] * inv : 0.f;
#pragma unroll
          for (int c = j + 1; c < KDIM; ++c) m[c] = fmaf(-f, lane_bcast(m[c], j), m[c]);
          rhs = fmaf(-f, lane_bcast(rhs, j), rhs);
          if (r == j) myinv = inv;
        }
      }
      return rhs * myinv;  // inactive rows -> exact 0
    } else {
      // ---- removed-set GJ on G = AtA^-1: G_RR u = y_R; z = y - G[:,R] u ----
      const bool reml = (Rm >> r) & 1u;
      float m[KDIM];
#pragma unroll
      for (int c = 0; c < KDIM; ++c)
        m[c] = (reml && ((Rm >> c) & 1u)) ? g[c] : ((r == c) ? 1.f : 0.f);
      float rhs = reml ? y : 0.f;
      float myinv = 0.f;
#pragma unroll
      for (int j = 0; j < KDIM; ++j) {
        if ((Rm >> j) & 1u) {
          const float inv = rcp_fast(lane_bcast(m[j], j));
          const float f = (r != j) ? m[j] * inv : 0.f;
#pragma unroll
          for (int c = j + 1; c < KDIM; ++c) m[c] = fmaf(-f, lane_bcast(m[c], j), m[c]);
          rhs = fmaf(-f, lane_bcast(rhs, j), rhs);
          if (r == j) myinv = inv;
        }
      }
      const float u = rhs * myinv;  // u_c = 0 for c notin R
      float z0 = y, z1 = 0.f, z2 = 0.f, z3 = 0.f;
#pragma unroll
      for (int c = 0; c < KDIM; c += 4) {
        z0 = fmaf(-g[c + 0], lane_bcast(u, c + 0), z0);
        z1 = fmaf(-g[c + 1], lane_bcast(u, c + 1), z1);
        z2 = fmaf(-g[c + 2], lane_bcast(u, c + 2), z2);
        z3 = fmaf(-g[c + 3], lane_bcast(u, c + 3), z3);
      }
      return (z0 + z1) + (z2 + z3);  // removed rows -> ~0 (roundoff only)
    }
  };

  // ---- init ----
  unsigned int P = (unsigned int)(__ballot(atb > 1e-6f) & 0xffffffffull);
  float z = (P == 0xffffffffu) ? y : solve_dual(P);

  // ---- annealed-threshold block principal pivoting (cap 24, stag>=1) ----
  float zeps = 0.f, weps = W_TOL;
  int best = 1000;
  for (int it = 0; it < 24; ++it) {
    const bool act = (P >> r) & 1u;
    // w = atb - AtA z (z ~0 on inactive rows), 4 chains for latency
    float s0 = 0.f, s1 = 0.f, s2 = 0.f, s3 = 0.f;
#pragma unroll
    for (int c = 0; c < KDIM; c += 4) {
      s0 = fmaf(ata[c + 0], lane_bcast(z, c + 0), s0);
      s1 = fmaf(ata[c + 1], lane_bcast(z, c + 1), s1);
      s2 = fmaf(ata[c + 2], lane_bcast(z, c + 2), s2);
      s3 = fmaf(ata[c + 3], lane_bcast(z, c + 3), s3);
    }
    const float w = atb - ((s0 + s1) + (s2 + s3));
    // single ballot: infeasibility per lane (active: z too negative;
    // inactive: gradient above add threshold)
    const bool pred = act ? (z < -zeps) : (w > weps);
    const unsigned int u = (unsigned int)(__ballot(pred) & 0xffffffffull);
    if (u == 0u) break;  // annealed-KKT satisfied (uniform)
    const int ninf = __popc(u);
    if (ninf < best) {
      best = ninf;
    } else {  // non-improving round: escalate immediately (kills cycling tail)
      zeps = fminf(zeps * 4.f + 2e-6f, 2.5e-4f);
      weps *= 4.f;
    }
    P = (P & ~(u & P)) | (u & ~P);  // block flip: drop bad, add violators
    z = solve_dual(P);
  }

  if (l < KDIM) S[r * NDIM + n] = ((P >> r) & 1u) ? fmaxf(z, 0.f) : 0.f;
}

extern "C" void kernel_launch(void* const* d_in, const int* in_sizes, int n_in,
                              void* d_out, int out_size, void* d_ws, size_t ws_size,
                              hipStream_t stream) {
  const float* X = (const float*)d_in[0];  // [256, 2048]
  const float* A = (const float*)d_in[1];  // [256, 32]
  float* S = (float*)d_out;                // [32, 2048]
  float* AtA = (float*)d_ws;               // 1024 floats
  float* Ainv = AtA + KDIM * KDIM;         // 1024 floats
  float* part = Ainv + KDIM * KDIM;        // 8*1024 floats

  ata_partial<<<8, 1024, 0, stream>>>(A, part);
  inv_kernel<<<1, 64, 0, stream>>>(part, AtA, Ainv);
  nnls_kernel<<<NDIM, 64, 0, stream>>>(A, AtA, Ainv, X, S);
}

// Round 14
// 40.762 us; speedup vs baseline: 1.8608x; 1.0096x over previous
//
#include <hip/hip_runtime.h>
#include <math.h>

#define KDIM 32
#define MDIM 256
#define NDIM 2048
#define W_TOL 1e-3f   // base add threshold (hysteresis vs z-removal at ~0:
                      // cycling needs sensitivity d_j > W_TOL/Z ~ impossible,
                      // solution shift <= W_TOL/lambda_min ~ 1e-5 << 3e-3)

// ---------------- helpers ----------------
__device__ __forceinline__ float lane_bcast(float x, int lane) {
  return __int_as_float(__builtin_amdgcn_readlane(__float_as_int(x), lane));
}
__device__ __forceinline__ float rcp_newton(float x) {
  float r;
  asm("v_rcp_f32 %0, %1" : "=v"(r) : "v"(x));
  r = r * (2.0f - x * r);  // one Newton step (shared inverse only)
  return r;
}
__device__ __forceinline__ float rcp_fast(float x) {
  float r;
  asm("v_rcp_f32 %0, %1" : "=v"(r) : "v"(x));
  return r;  // ~1 ulp; fine vs 3e-3 threshold (kappa ~ 56 both modes)
}

// ---------------- AtA partials: 8 blocks, each reduces 32 rows of A ------------
__global__ __launch_bounds__(1024) void ata_partial(const float* __restrict__ A,
                                                    float* __restrict__ part) {
  __shared__ float As[32 * KDIM];  // 4 KB slice
  const int t = threadIdx.x, g = blockIdx.x;
  As[t] = A[g * 32 * KDIM + t];  // coalesced
  __syncthreads();
  const int i = t >> 5, j = t & 31;
  float acc = 0.f;
#pragma unroll
  for (int mm = 0; mm < 32; ++mm)
    acc = fmaf(As[mm * KDIM + i], As[mm * KDIM + j], acc);  // bcast+consecutive: conflict-free
  part[g * 1024 + t] = acc;
}

// ---------------- sum partials -> AtA; full inverse via Gauss-Jordan ----------
__global__ __launch_bounds__(64) void inv_kernel(const float* __restrict__ part,
                                                 float* __restrict__ AtA,
                                                 float* __restrict__ Ainv) {
  __shared__ float AtAs[KDIM * 33];  // padded
  const int l = threadIdx.x;
  const int r = l & 31;
#pragma unroll
  for (int q4 = 0; q4 < 4; ++q4) {
    const int f4 = q4 * 64 + l;
    float4 s = {0.f, 0.f, 0.f, 0.f};
#pragma unroll
    for (int g = 0; g < 8; ++g) {
      const float4 v = reinterpret_cast<const float4*>(part)[g * 256 + f4];
      s.x += v.x; s.y += v.y; s.z += v.z; s.w += v.w;
    }
    reinterpret_cast<float4*>(AtA)[f4] = s;
    const int e = f4 * 4, row = e >> 5, col = e & 31;
    AtAs[row * 33 + col + 0] = s.x;
    AtAs[row * 33 + col + 1] = s.y;
    AtAs[row * 33 + col + 2] = s.z;
    AtAs[row * 33 + col + 3] = s.w;
  }
  __syncthreads();
  float m[KDIM], g[KDIM];
#pragma unroll
  for (int c = 0; c < KDIM; ++c) {
    m[c] = AtAs[r * 33 + c];
    g[c] = (r == c) ? 1.f : 0.f;
  }
  float myinv = 0.f;
#pragma unroll
  for (int j = 0; j < KDIM; ++j) {
    const float inv = rcp_newton(lane_bcast(m[j], j));
    const float f = (r != j) ? m[j] * inv : 0.f;
#pragma unroll
    for (int c = j + 1; c < KDIM; ++c) m[c] = fmaf(-f, lane_bcast(m[c], j), m[c]);
#pragma unroll
    for (int c = 0; c < KDIM; ++c) g[c] = fmaf(-f, lane_bcast(g[c], j), g[c]);
    if (r == j) myinv = inv;
  }
  if (l < 32) {
#pragma unroll
    for (int c = 0; c < KDIM; ++c) Ainv[r * KDIM + c] = myinv * g[c];
  }
}

// ---------------- per-column NNLS, one wave per column -------------------------
// Lane l owns row r=l&31; hi half mirrors lo so all branches are wave-uniform.
// Solver: annealed-threshold block principal pivoting, HARD-CAPPED at 8 rounds,
// then a freeze finisher: drop stubborn negatives (z < -2.5e-4), one final
// solve, clip at output. Rationale (R13 post-mortem): straggler waves spent
// ~24 rounds ping-ponging threshold-scale variables (|z|~1e-5, w~1e-3) whose
// effect on the output is ~1e-4; kernel time = straggler rounds x solve cost.
// Error budget: dropped/clipped <= 2.5e-4; missed adds w <= ~4e-3 -> dz <=
// 4e-5; coupling <= 1e-4. All << 3e-3. Masked solves: min(p,q)-pivot dual
// formulation (active-set GJ on AtA, or removed-set GJ on G = AtA^-1).
__global__ __launch_bounds__(64, 2) void nnls_kernel(const float* __restrict__ A,
                                                     const float* __restrict__ AtA_g,
                                                     const float* __restrict__ Ainv_g,
                                                     const float* __restrict__ X,
                                                     float* __restrict__ S) {
  const int l = threadIdx.x;
  const int r = l & 31;
  const int n = blockIdx.x;

  // ---- Atb = A^T X[:, n] ----
  float x4[4];
#pragma unroll
  for (int q = 0; q < 4; ++q) x4[q] = X[(q * 64 + l) * NDIM + n];
  float cur[KDIM];
#pragma unroll
  for (int k = 0; k < KDIM; ++k) cur[k] = 0.f;
#pragma unroll
  for (int q = 0; q < 4; ++q) {
    const int m = q * 64 + l;
#pragma unroll
    for (int qq = 0; qq < 8; ++qq) {
      const float4 a4 = reinterpret_cast<const float4*>(A + m * KDIM)[qq];
      cur[4 * qq + 0] = fmaf(a4.x, x4[q], cur[4 * qq + 0]);
      cur[4 * qq + 1] = fmaf(a4.y, x4[q], cur[4 * qq + 1]);
      cur[4 * qq + 2] = fmaf(a4.z, x4[q], cur[4 * qq + 2]);
      cur[4 * qq + 3] = fmaf(a4.w, x4[q], cur[4 * qq + 3]);
    }
  }
#pragma unroll
  for (int k = 0; k < KDIM; ++k) cur[k] += __shfl_xor(cur[k], 32);
#pragma unroll
  for (int o = 16; o >= 1; o >>= 1) {
#pragma unroll
    for (int i = 0; i < o; ++i) {
      const bool hi = (l & o) != 0;
      const float a = cur[i], b = cur[i + o];
      const float mine = hi ? b : a;
      const float send = hi ? a : b;
      cur[i] = mine + __shfl_xor(send, o);
    }
  }
  const float atb = cur[0];  // Atb[r], mirrored in hi half

  // ---- shared AtA row + Ainv row ----
  float ata[KDIM], g[KDIM];
#pragma unroll
  for (int q = 0; q < KDIM / 4; ++q) {
    const float4 v = reinterpret_cast<const float4*>(AtA_g + r * KDIM)[q];
    ata[4 * q + 0] = v.x; ata[4 * q + 1] = v.y; ata[4 * q + 2] = v.z; ata[4 * q + 3] = v.w;
    const float4 u = reinterpret_cast<const float4*>(Ainv_g + r * KDIM)[q];
    g[4 * q + 0] = u.x; g[4 * q + 1] = u.y; g[4 * q + 2] = u.z; g[4 * q + 3] = u.w;
  }

  // ---- y = Ainv @ Atb (unconstrained solution; 4 chains for latency) ----
  float y;
  {
    float s0 = 0.f, s1 = 0.f, s2 = 0.f, s3 = 0.f;
#pragma unroll
    for (int c = 0; c < KDIM; c += 4) {
      s0 = fmaf(g[c + 0], lane_bcast(atb, c + 0), s0);
      s1 = fmaf(g[c + 1], lane_bcast(atb, c + 1), s1);
      s2 = fmaf(g[c + 2], lane_bcast(atb, c + 2), s2);
      s3 = fmaf(g[c + 3], lane_bcast(atb, c + 3), s3);
    }
    y = (s0 + s1) + (s2 + s3);
  }

  // masked solve, min(p,q)-pivot dual formulation (registers + readlane only)
  auto solve_dual = [&](unsigned int Pm) -> float {
    const unsigned int Rm = ~Pm;  // removed set (bits 0..31)
    const int p = __popc(Pm);
    if (p <= 32 - p) {
      // ---- active-set GJ on AtA ----
      const bool actl = (Pm >> r) & 1u;
      float m[KDIM];
#pragma unroll
      for (int c = 0; c < KDIM; ++c)
        m[c] = (actl && ((Pm >> c) & 1u)) ? ata[c] : ((r == c) ? 1.f : 0.f);
      float rhs = actl ? atb : 0.f;
      float myinv = 0.f;
#pragma unroll
      for (int j = 0; j < KDIM; ++j) {
        if ((Pm >> j) & 1u) {
          const float inv = rcp_fast(lane_bcast(m[j], j));
          const float f = (r != j) ? m[j] * inv : 0.f;
#pragma unroll
          for (int c = j + 1; c < KDIM; ++c) m[c] = fmaf(-f, lane_bcast(m[c], j), m[c]);
          rhs = fmaf(-f, lane_bcast(rhs, j), rhs);
          if (r == j) myinv = inv;
        }
      }
      return rhs * myinv;  // inactive rows -> exact 0
    } else {
      // ---- removed-set GJ on G = AtA^-1: G_RR u = y_R; z = y - G[:,R] u ----
      const bool reml = (Rm >> r) & 1u;
      float m[KDIM];
#pragma unroll
      for (int c = 0; c < KDIM; ++c)
        m[c] = (reml && ((Rm >> c) & 1u)) ? g[c] : ((r == c) ? 1.f : 0.f);
      float rhs = reml ? y : 0.f;
      float myinv = 0.f;
#pragma unroll
      for (int j = 0; j < KDIM; ++j) {
        if ((Rm >> j) & 1u) {
          const float inv = rcp_fast(lane_bcast(m[j], j));
          const float f = (r != j) ? m[j] * inv : 0.f;
#pragma unroll
          for (int c = j + 1; c < KDIM; ++c) m[c] = fmaf(-f, lane_bcast(m[c], j), m[c]);
          rhs = fmaf(-f, lane_bcast(rhs, j), rhs);
          if (r == j) myinv = inv;
        }
      }
      const float u = rhs * myinv;  // u_c = 0 for c notin R
      float z0 = y, z1 = 0.f, z2 = 0.f, z3 = 0.f;
#pragma unroll
      for (int c = 0; c < KDIM; c += 4) {
        z0 = fmaf(-g[c + 0], lane_bcast(u, c + 0), z0);
        z1 = fmaf(-g[c + 1], lane_bcast(u, c + 1), z1);
        z2 = fmaf(-g[c + 2], lane_bcast(u, c + 2), z2);
        z3 = fmaf(-g[c + 3], lane_bcast(u, c + 3), z3);
      }
      return (z0 + z1) + (z2 + z3);  // removed rows -> ~0 (roundoff only)
    }
  };

  // ---- init ----
  unsigned int P = (unsigned int)(__ballot(atb > 1e-6f) & 0xffffffffull);
  float z = (P == 0xffffffffu) ? y : solve_dual(P);

  // ---- annealed-threshold block principal pivoting, hard cap 8 rounds ----
  float zeps = 0.f, weps = W_TOL;
  int best = 1000;
  bool conv = false;
  for (int it = 0; it < 8; ++it) {
    const bool act = (P >> r) & 1u;
    // w = atb - AtA z (z ~0 on inactive rows), 4 chains for latency
    float s0 = 0.f, s1 = 0.f, s2 = 0.f, s3 = 0.f;
#pragma unroll
    for (int c = 0; c < KDIM; c += 4) {
      s0 = fmaf(ata[c + 0], lane_bcast(z, c + 0), s0);
      s1 = fmaf(ata[c + 1], lane_bcast(z, c + 1), s1);
      s2 = fmaf(ata[c + 2], lane_bcast(z, c + 2), s2);
      s3 = fmaf(ata[c + 3], lane_bcast(z, c + 3), s3);
    }
    const float w = atb - ((s0 + s1) + (s2 + s3));
    const bool pred = act ? (z < -zeps) : (w > weps);
    const unsigned int u = (unsigned int)(__ballot(pred) & 0xffffffffull);
    if (u == 0u) { conv = true; break; }  // annealed-KKT satisfied (uniform)
    const int ninf = __popc(u);
    if (ninf < best) {
      best = ninf;
    } else {  // non-improving round: escalate immediately
      zeps = fminf(zeps * 4.f + 2e-6f, 2.5e-4f);
      weps *= 4.f;
    }
    P = (P & ~(u & P)) | (u & ~P);  // block flip: drop bad, add violators
    z = solve_dual(P);
  }

  // ---- freeze finisher for stragglers: drop stubborn negatives, one solve ----
  if (!conv) {
    const unsigned int drop =
        (unsigned int)(__ballot(((P >> r) & 1u) && (z < -2.5e-4f)) & 0xffffffffull);
    if (drop != 0u) {
      P &= ~drop;
      z = solve_dual(P);
    }
  }

  if (l < KDIM) S[r * NDIM + n] = ((P >> r) & 1u) ? fmaxf(z, 0.f) : 0.f;
}

extern "C" void kernel_launch(void* const* d_in, const int* in_sizes, int n_in,
                              void* d_out, int out_size, void* d_ws, size_t ws_size,
                              hipStream_t stream) {
  const float* X = (const float*)d_in[0];  // [256, 2048]
  const float* A = (const float*)d_in[1];  // [256, 32]
  float* S = (float*)d_out;                // [32, 2048]
  float* AtA = (float*)d_ws;               // 1024 floats
  float* Ainv = AtA + KDIM * KDIM;         // 1024 floats
  float* part = Ainv + KDIM * KDIM;        // 8*1024 floats

  ata_partial<<<8, 1024, 0, stream>>>(A, part);
  inv_kernel<<<1, 64, 0, stream>>>(part, AtA, Ainv);
  nnls_kernel<<<NDIM, 64, 0, stream>>>(A, AtA, Ainv, X, S);
}

// Round 15
// 32.479 us; speedup vs baseline: 2.3354x; 1.2550x over previous
//
#include <hip/hip_runtime.h>
#include <math.h>

#define KDIM 32
#define MDIM 256
#define NDIM 2048
#define W_TOL 1e-3f   // base add threshold (hysteresis; solution shift <= W_TOL/lambda_min ~ 1e-5)

// ---------------- helpers ----------------
__device__ __forceinline__ float lane_bcast(float x, int lane) {
  return __int_as_float(__builtin_amdgcn_readlane(__float_as_int(x), lane));
}
__device__ __forceinline__ float rcp_newton(float x) {
  float r;
  asm("v_rcp_f32 %0, %1" : "=v"(r) : "v"(x));
  r = r * (2.0f - x * r);  // one Newton step (shared inverse only)
  return r;
}
__device__ __forceinline__ float rcp_fast(float x) {
  float r;
  asm("v_rcp_f32 %0, %1" : "=v"(r) : "v"(x));
  return r;  // ~1 ulp; fine vs 3e-3 threshold (kappa ~ 56 both modes)
}

// ---------------- prep: AtXt (blocks 0..63) + AtA & inverse (block 64) ---------
// One launch replaces {ata_partial, inv_kernel, nnls-Atb-prologue}. The serial
// 1-wave GJ inverse runs concurrently with the 64 AtX blocks.
__global__ __launch_bounds__(256) void prep_kernel(const float* __restrict__ A,
                                                   const float* __restrict__ X,
                                                   float* __restrict__ AtA,
                                                   float* __restrict__ Ainv,
                                                   float* __restrict__ AtXt) {
  __shared__ float buf[8448];  // 33 KB: A staging (8192), then reused
  const int t = threadIdx.x;
  // stage A (256x32 = 8192 floats) coalesced: 8 float4 per thread
  {
    const float4* A4 = reinterpret_cast<const float4*>(A);
    float4* B4 = reinterpret_cast<float4*>(buf);
#pragma unroll
    for (int i = 0; i < 8; ++i) B4[t + 256 * i] = A4[t + 256 * i];
  }
  __syncthreads();

  if (blockIdx.x < 64) {
    // ---- AtXt[n][k] for 32 columns; 8-way m-split across 256 threads ----
    const int nl = t & 31;     // column within block
    const int ch = t >> 5;     // m-chunk 0..7
    const int n = blockIdx.x * 32 + nl;
    float acc[KDIM];
#pragma unroll
    for (int k = 0; k < KDIM; ++k) acc[k] = 0.f;
#pragma unroll 4
    for (int mm = 0; mm < 32; ++mm) {
      const int m = ch * 32 + mm;
      const float x = X[m * NDIM + n];  // 2 coalesced 128B segments per instr
#pragma unroll
      for (int qq = 0; qq < 8; ++qq) {
        const float4 a4 = *reinterpret_cast<const float4*>(&buf[m * KDIM + qq * 4]);
        acc[4 * qq + 0] = fmaf(a4.x, x, acc[4 * qq + 0]);  // LDS broadcast reads
        acc[4 * qq + 1] = fmaf(a4.y, x, acc[4 * qq + 1]);
        acc[4 * qq + 2] = fmaf(a4.z, x, acc[4 * qq + 2]);
        acc[4 * qq + 3] = fmaf(a4.w, x, acc[4 * qq + 3]);
      }
    }
    __syncthreads();  // done reading A; reuse buf as red[ch][nl][33]
#pragma unroll
    for (int k = 0; k < KDIM; ++k) buf[ch * 1056 + nl * 33 + k] = acc[k];  // bank = nl: clean
    __syncthreads();
    // reduce 8 chunks; 4 outputs/thread; store coalesced float4 ([n][k] layout)
    float v[4];
#pragma unroll
    for (int q = 0; q < 4; ++q) {
      const int f = t * 4 + q, kk = f & 31, nn = f >> 5;
      float s = 0.f;
#pragma unroll
      for (int g = 0; g < 8; ++g) s += buf[g * 1056 + nn * 33 + kk];
      v[q] = s;
    }
    const float4 o = {v[0], v[1], v[2], v[3]};
    reinterpret_cast<float4*>(AtXt + blockIdx.x * 32 * KDIM)[t] = o;
  } else {
    // ---- AtA (4 outputs/thread, LDS broadcast) then 1-wave GJ inverse ----
    const int i = t >> 3, j0 = (t & 7) * 4;
    float a0 = 0.f, a1 = 0.f, a2 = 0.f, a3 = 0.f;
    for (int m = 0; m < MDIM; ++m) {
      const float ai = buf[m * KDIM + i];
      const float4 vj = *reinterpret_cast<const float4*>(&buf[m * KDIM + j0]);
      a0 = fmaf(ai, vj.x, a0);
      a1 = fmaf(ai, vj.y, a1);
      a2 = fmaf(ai, vj.z, a2);
      a3 = fmaf(ai, vj.w, a3);
    }
    __syncthreads();  // all done reading A
    {
      const float4 o = {a0, a1, a2, a3};
      reinterpret_cast<float4*>(AtA)[t] = o;  // flat index 4t == i*32+j0
    }
    buf[i * 33 + j0 + 0] = a0;  // padded AtAs for the inverse wave
    buf[i * 33 + j0 + 1] = a1;
    buf[i * 33 + j0 + 2] = a2;
    buf[i * 33 + j0 + 3] = a3;
    __syncthreads();
    if (t < 64) {
      const int r = t & 31;
      float m_[KDIM], g_[KDIM];
#pragma unroll
      for (int c = 0; c < KDIM; ++c) {
        m_[c] = buf[r * 33 + c];  // bank (r+c)%32: conflict-free
        g_[c] = (r == c) ? 1.f : 0.f;
      }
      float myinv = 0.f;
#pragma unroll
      for (int j = 0; j < KDIM; ++j) {
        const float inv = rcp_newton(lane_bcast(m_[j], j));
        const float f = (r != j) ? m_[j] * inv : 0.f;
#pragma unroll
        for (int c = j + 1; c < KDIM; ++c) m_[c] = fmaf(-f, lane_bcast(m_[c], j), m_[c]);
#pragma unroll
        for (int c = 0; c < KDIM; ++c) g_[c] = fmaf(-f, lane_bcast(g_[c], j), g_[c]);
        if (r == j) myinv = inv;
      }
      if (t < 32) {
#pragma unroll
        for (int c = 0; c < KDIM; ++c) Ainv[r * KDIM + c] = myinv * g_[c];
      }
    }
  }
}

// ---------------- per-column NNLS, one wave per column -------------------------
// Lane l owns row r=l&31; hi half mirrors lo so all branches are wave-uniform.
// Atb arrives precomputed (one coalesced 128B load). Solver: annealed-threshold
// block principal pivoting, hard cap 8 rounds, then freeze finisher (R14-proven).
// Masked solves: min(p,q)-pivot dual formulation (active-set GJ on AtA, or
// removed-set GJ on G = AtA^-1: z = y - G[:,R] (G_RR)^-1 y_R).
__global__ __launch_bounds__(64, 2) void nnls_kernel(const float* __restrict__ AtA_g,
                                                     const float* __restrict__ Ainv_g,
                                                     const float* __restrict__ AtXt,
                                                     float* __restrict__ S) {
  const int l = threadIdx.x;
  const int r = l & 31;
  const int n = blockIdx.x;

  const float atb = AtXt[n * KDIM + r];  // coalesced; hi half same line

  // ---- shared AtA row + Ainv row ----
  float ata[KDIM], g[KDIM];
#pragma unroll
  for (int q = 0; q < KDIM / 4; ++q) {
    const float4 v = reinterpret_cast<const float4*>(AtA_g + r * KDIM)[q];
    ata[4 * q + 0] = v.x; ata[4 * q + 1] = v.y; ata[4 * q + 2] = v.z; ata[4 * q + 3] = v.w;
    const float4 u = reinterpret_cast<const float4*>(Ainv_g + r * KDIM)[q];
    g[4 * q + 0] = u.x; g[4 * q + 1] = u.y; g[4 * q + 2] = u.z; g[4 * q + 3] = u.w;
  }

  // ---- y = Ainv @ Atb (unconstrained solution; 4 chains for latency) ----
  float y;
  {
    float s0 = 0.f, s1 = 0.f, s2 = 0.f, s3 = 0.f;
#pragma unroll
    for (int c = 0; c < KDIM; c += 4) {
      s0 = fmaf(g[c + 0], lane_bcast(atb, c + 0), s0);
      s1 = fmaf(g[c + 1], lane_bcast(atb, c + 1), s1);
      s2 = fmaf(g[c + 2], lane_bcast(atb, c + 2), s2);
      s3 = fmaf(g[c + 3], lane_bcast(atb, c + 3), s3);
    }
    y = (s0 + s1) + (s2 + s3);
  }

  // masked solve, min(p,q)-pivot dual formulation (registers + readlane only)
  auto solve_dual = [&](unsigned int Pm) -> float {
    const unsigned int Rm = ~Pm;  // removed set (bits 0..31)
    const int p = __popc(Pm);
    if (p <= 32 - p) {
      // ---- active-set GJ on AtA ----
      const bool actl = (Pm >> r) & 1u;
      float m[KDIM];
#pragma unroll
      for (int c = 0; c < KDIM; ++c)
        m[c] = (actl && ((Pm >> c) & 1u)) ? ata[c] : ((r == c) ? 1.f : 0.f);
      float rhs = actl ? atb : 0.f;
      float myinv = 0.f;
#pragma unroll
      for (int j = 0; j < KDIM; ++j) {
        if ((Pm >> j) & 1u) {
          const float inv = rcp_fast(lane_bcast(m[j], j));
          const float f = (r != j) ? m[j] * inv : 0.f;
#pragma unroll
          for (int c = j + 1; c < KDIM; ++c) m[c] = fmaf(-f, lane_bcast(m[c], j), m[c]);
          rhs = fmaf(-f, lane_bcast(rhs, j), rhs);
          if (r == j) myinv = inv;
        }
      }
      return rhs * myinv;  // inactive rows -> exact 0
    } else {
      // ---- removed-set GJ on G = AtA^-1: G_RR u = y_R; z = y - G[:,R] u ----
      const bool reml = (Rm >> r) & 1u;
      float m[KDIM];
#pragma unroll
      for (int c = 0; c < KDIM; ++c)
        m[c] = (reml && ((Rm >> c) & 1u)) ? g[c] : ((r == c) ? 1.f : 0.f);
      float rhs = reml ? y : 0.f;
      float myinv = 0.f;
#pragma unroll
      for (int j = 0; j < KDIM; ++j) {
        if ((Rm >> j) & 1u) {
          const float inv = rcp_fast(lane_bcast(m[j], j));
          const float f = (r != j) ? m[j] * inv : 0.f;
#pragma unroll
          for (int c = j + 1; c < KDIM; ++c) m[c] = fmaf(-f, lane_bcast(m[c], j), m[c]);
          rhs = fmaf(-f, lane_bcast(rhs, j), rhs);
          if (r == j) myinv = inv;
        }
      }
      const float u = rhs * myinv;  // u_c = 0 for c notin R
      float z0 = y, z1 = 0.f, z2 = 0.f, z3 = 0.f;
#pragma unroll
      for (int c = 0; c < KDIM; c += 4) {
        z0 = fmaf(-g[c + 0], lane_bcast(u, c + 0), z0);
        z1 = fmaf(-g[c + 1], lane_bcast(u, c + 1), z1);
        z2 = fmaf(-g[c + 2], lane_bcast(u, c + 2), z2);
        z3 = fmaf(-g[c + 3], lane_bcast(u, c + 3), z3);
      }
      return (z0 + z1) + (z2 + z3);  // removed rows -> ~0 (roundoff only)
    }
  };

  // ---- init ----
  unsigned int P = (unsigned int)(__ballot(atb > 1e-6f) & 0xffffffffull);
  float z = (P == 0xffffffffu) ? y : solve_dual(P);

  // ---- annealed-threshold block principal pivoting, hard cap 8 rounds ----
  float zeps = 0.f, weps = W_TOL;
  int best = 1000;
  bool conv = false;
  for (int it = 0; it < 8; ++it) {
    const bool act = (P >> r) & 1u;
    float s0 = 0.f, s1 = 0.f, s2 = 0.f, s3 = 0.f;
#pragma unroll
    for (int c = 0; c < KDIM; c += 4) {
      s0 = fmaf(ata[c + 0], lane_bcast(z, c + 0), s0);
      s1 = fmaf(ata[c + 1], lane_bcast(z, c + 1), s1);
      s2 = fmaf(ata[c + 2], lane_bcast(z, c + 2), s2);
      s3 = fmaf(ata[c + 3], lane_bcast(z, c + 3), s3);
    }
    const float w = atb - ((s0 + s1) + (s2 + s3));
    const bool pred = act ? (z < -zeps) : (w > weps);
    const unsigned int u = (unsigned int)(__ballot(pred) & 0xffffffffull);
    if (u == 0u) { conv = true; break; }  // annealed-KKT satisfied (uniform)
    const int ninf = __popc(u);
    if (ninf < best) {
      best = ninf;
    } else {  // non-improving round: escalate immediately
      zeps = fminf(zeps * 4.f + 2e-6f, 2.5e-4f);
      weps *= 4.f;
    }
    P = (P & ~(u & P)) | (u & ~P);  // block flip: drop bad, add violators
    z = solve_dual(P);
  }

  // ---- freeze finisher for stragglers: drop stubborn negatives, one solve ----
  if (!conv) {
    const unsigned int drop =
        (unsigned int)(__ballot(((P >> r) & 1u) && (z < -2.5e-4f)) & 0xffffffffull);
    if (drop != 0u) {
      P &= ~drop;
      z = solve_dual(P);
    }
  }

  if (l < KDIM) S[r * NDIM + n] = ((P >> r) & 1u) ? fmaxf(z, 0.f) : 0.f;
}

extern "C" void kernel_launch(void* const* d_in, const int* in_sizes, int n_in,
                              void* d_out, int out_size, void* d_ws, size_t ws_size,
                              hipStream_t stream) {
  const float* X = (const float*)d_in[0];  // [256, 2048]
  const float* A = (const float*)d_in[1];  // [256, 32]
  float* S = (float*)d_out;                // [32, 2048]
  float* AtA = (float*)d_ws;               // 1024 floats
  float* Ainv = AtA + KDIM * KDIM;         // 1024 floats
  float* AtXt = Ainv + KDIM * KDIM;        // 65536 floats, [n][k]

  prep_kernel<<<65, 256, 0, stream>>>(A, X, AtA, Ainv, AtXt);
  nnls_kernel<<<NDIM, 64, 0, stream>>>(AtA, Ainv, AtXt, S);
}